// Round 1
// baseline (2439.848 us; speedup 1.0000x reference)
//
#include <hip/hip_runtime.h>
#include <cstddef>

#define SS 2048
#define BB 256
#define II 64
#define HH 128

// One workgroup per batch element. 512 threads = 8 waves.
// slice = tid&7 : j-slice (16 of 128 for w_hh, 8 of 64 for w_ih)
// idx   = tid>>3: owns hidden indices {idx, idx+64}, each with 3 gate rows.
__global__ __launch_bounds__(512) void gru_fused(
    const float* __restrict__ x,        // [B,S,I]
    const int*   __restrict__ mask,     // [B,S,I]
    const float* __restrict__ x_mean,   // [I]
    const float* __restrict__ w_ih,     // [3H,I]
    const float* __restrict__ w_hh,     // [3H,H]
    const float* __restrict__ b_ih,     // [3H]
    const float* __restrict__ b_hh,     // [3H]
    const float* __restrict__ bn_gamma, // [H]
    const float* __restrict__ bn_beta,  // [H]
    const float* __restrict__ bn_mean,  // [H]
    const float* __restrict__ bn_var,   // [H]
    const float* __restrict__ fc_w,     // [1,H]
    const float* __restrict__ fc_b,     // [1]
    float* __restrict__ out)            // [B,1]
{
  const int b     = blockIdx.x;
  const int tid   = threadIdx.x;
  const int slice = tid & 7;
  const int idx   = tid >> 3;
  const int hx0   = idx;
  const int hx1   = idx + 64;

  __shared__ __align__(16) float xi_lds[II];
  __shared__ __align__(16) float h_buf[HH];
  __shared__ float wred[8];

  // ---- load weights into registers (one time) ----
  float wh[6][16];  // rows: u*3+g, g in {r,z,n}, u in {hx0,hx1}; 16-wide j-slice
  float wi[6][8];   // 8-wide i-slice
  #pragma unroll
  for (int u = 0; u < 2; ++u) {
    const int hh = u ? hx1 : hx0;
    #pragma unroll
    for (int g = 0; g < 3; ++g) {
      const float* pr = w_hh + (size_t)(g * HH + hh) * HH + slice * 16;
      #pragma unroll
      for (int q = 0; q < 4; ++q) {
        float4 v = *reinterpret_cast<const float4*>(pr + q * 4);
        wh[u*3+g][q*4+0] = v.x; wh[u*3+g][q*4+1] = v.y;
        wh[u*3+g][q*4+2] = v.z; wh[u*3+g][q*4+3] = v.w;
      }
      const float* pi = w_ih + (size_t)(g * HH + hh) * II + slice * 8;
      #pragma unroll
      for (int q = 0; q < 2; ++q) {
        float4 v = *reinterpret_cast<const float4*>(pi + q * 4);
        wi[u*3+g][q*4+0] = v.x; wi[u*3+g][q*4+1] = v.y;
        wi[u*3+g][q*4+2] = v.z; wi[u*3+g][q*4+3] = v.w;
      }
    }
  }

  // biases folded into slice 0's accumulator init
  float bR[2], bZ[2], bNX[2], bNH[2];
  const bool lead = (slice == 0);
  #pragma unroll
  for (int u = 0; u < 2; ++u) {
    const int hh = u ? hx1 : hx0;
    bR[u]  = lead ? (b_ih[hh]        + b_hh[hh])        : 0.f;
    bZ[u]  = lead ? (b_ih[HH + hh]   + b_hh[HH + hh])   : 0.f;
    bNX[u] = lead ?  b_ih[2*HH + hh]                    : 0.f;
    bNH[u] = lead ?  b_hh[2*HH + hh]                    : 0.f;
  }

  // ---- prologue: LOCF state + first prefetch ----
  const size_t xbase = (size_t)b * SS * II;
  float last = 0.f, xn = 0.f;
  int   mn = 0;
  if (tid < II) {
    last = x_mean[tid];
    xn   = x[xbase + tid];
    mn   = mask[xbase + tid];
  }
  float hnA = 0.f, hnB = 0.f;  // h[-1] = 0

  for (int t = 0; t < SS; ++t) {
    // (a) write window: publish xi[t] and h[t-1]
    if (tid < II) {
      last = (mn > 0) ? xn : last;
      xi_lds[tid] = last;
    }
    if (slice == 0) { h_buf[hx0] = hnA; h_buf[hx1] = hnB; }
    __syncthreads();  // (b)

    // (c) prefetch t+1
    if (tid < II && t + 1 < SS) {
      const size_t o = xbase + (size_t)(t + 1) * II + tid;
      xn = x[o];
      mn = mask[o];
    }

    // (d) compute
    const float hp0 = h_buf[hx0];
    const float hp1 = h_buf[hx1];

    float xv[8], hv[16];
    #pragma unroll
    for (int q = 0; q < 2; ++q) {
      float4 v = *reinterpret_cast<const float4*>(&xi_lds[slice * 8 + q * 4]);
      xv[q*4+0] = v.x; xv[q*4+1] = v.y; xv[q*4+2] = v.z; xv[q*4+3] = v.w;
    }
    #pragma unroll
    for (int q = 0; q < 4; ++q) {
      float4 v = *reinterpret_cast<const float4*>(&h_buf[slice * 16 + q * 4]);
      hv[q*4+0] = v.x; hv[q*4+1] = v.y; hv[q*4+2] = v.z; hv[q*4+3] = v.w;
    }

    float sR[2], sZ[2], sNX[2], sNH[2];
    #pragma unroll
    for (int u = 0; u < 2; ++u) {
      float ar = 0.f, az = 0.f, anh = 0.f;
      float axr = 0.f, axz = 0.f, anx = 0.f;
      #pragma unroll
      for (int j = 0; j < 16; ++j) {
        ar  += wh[u*3+0][j] * hv[j];
        az  += wh[u*3+1][j] * hv[j];
        anh += wh[u*3+2][j] * hv[j];
      }
      #pragma unroll
      for (int i2 = 0; i2 < 8; ++i2) {
        axr += wi[u*3+0][i2] * xv[i2];
        axz += wi[u*3+1][i2] * xv[i2];
        anx += wi[u*3+2][i2] * xv[i2];
      }
      sR[u]  = ar + axr + bR[u];
      sZ[u]  = az + axz + bZ[u];
      sNX[u] = anx + bNX[u];
      sNH[u] = anh + bNH[u];
    }

    // butterfly reduce over the 8 slices (lanes tid^1, ^2, ^4)
    #pragma unroll
    for (int m = 1; m < 8; m <<= 1) {
      #pragma unroll
      for (int u = 0; u < 2; ++u) {
        sR[u]  += __shfl_xor(sR[u],  m);
        sZ[u]  += __shfl_xor(sZ[u],  m);
        sNX[u] += __shfl_xor(sNX[u], m);
        sNH[u] += __shfl_xor(sNH[u], m);
      }
    }

    // gates (computed redundantly by all 8 slices; slice 0 publishes)
    {
      float r0 = 1.f / (1.f + __expf(-sR[0]));
      float z0 = 1.f / (1.f + __expf(-sZ[0]));
      float a0 = sNX[0] + r0 * sNH[0];
      a0 = fminf(fmaxf(a0, -15.f), 15.f);
      float e0 = __expf(2.f * a0);
      float n0 = (e0 - 1.f) / (e0 + 1.f);
      hnA = (1.f - z0) * n0 + z0 * hp0;

      float r1 = 1.f / (1.f + __expf(-sR[1]));
      float z1 = 1.f / (1.f + __expf(-sZ[1]));
      float a1 = sNX[1] + r1 * sNH[1];
      a1 = fminf(fmaxf(a1, -15.f), 15.f);
      float e1 = __expf(2.f * a1);
      float n1 = (e1 - 1.f) / (e1 + 1.f);
      hnB = (1.f - z1) * n1 + z1 * hp1;
    }
    __syncthreads();  // (e)
  }

  // publish final h
  if (slice == 0) { h_buf[hx0] = hnA; h_buf[hx1] = hnB; }
  __syncthreads();

  // BN (eval) + FC, reduced by wave 0
  if (tid < 64) {
    float p = 0.f;
    #pragma unroll
    for (int q = 0; q < 2; ++q) {
      const int k = tid + q * 64;
      const float hv2 = h_buf[k];
      const float nrm = (hv2 - bn_mean[k]) * rsqrtf(bn_var[k] + 1e-5f) * bn_gamma[k] + bn_beta[k];
      p += nrm * fc_w[k];
    }
    #pragma unroll
    for (int off = 32; off > 0; off >>= 1) p += __shfl_down(p, off);
    if (tid == 0) out[b] = p + fc_b[0];
  }
}

extern "C" void kernel_launch(void* const* d_in, const int* in_sizes, int n_in,
                              void* d_out, int out_size, void* d_ws, size_t ws_size,
                              hipStream_t stream) {
  const float* x        = (const float*)d_in[0];
  const int*   mask     = (const int*)  d_in[1];
  // d_in[2] = delta (unused by reference forward)
  const float* x_mean   = (const float*)d_in[3];
  const float* w_ih     = (const float*)d_in[4];
  const float* w_hh     = (const float*)d_in[5];
  const float* b_ih     = (const float*)d_in[6];
  const float* b_hh     = (const float*)d_in[7];
  const float* bn_gamma = (const float*)d_in[8];
  const float* bn_beta  = (const float*)d_in[9];
  const float* bn_mean  = (const float*)d_in[10];
  const float* bn_var   = (const float*)d_in[11];
  const float* fc_w     = (const float*)d_in[12];
  const float* fc_b     = (const float*)d_in[13];
  float* out = (float*)d_out;

  gru_fused<<<dim3(BB), dim3(512), 0, stream>>>(
      x, mask, x_mean, w_ih, w_hh, b_ih, b_hh,
      bn_gamma, bn_beta, bn_mean, bn_var, fc_w, fc_b, out);
}